// Round 10
// baseline (60.860 us; speedup 1.0000x reference)
//
#include <hip/hip_runtime.h>
#include <cfloat>

typedef float f32x16 __attribute__((ext_vector_type(16)));
typedef short s16x8  __attribute__((ext_vector_type(8)));

// Problem constants
constexpr int B = 4, N = 8192;
constexpr int IB   = 4;              // 32-row i-blocks per wave (minimized-over side)
constexpr int JT   = 8;              // 32-col j-tiles per wave (output side)
constexpr int ISTR = N / (32 * IB);  // 64 i-strips
constexpr int JSTR = N / (32 * JT);  // 32 j-strips
constexpr int NSEG = 2 * B;          // 8 (dir,b) segments

__device__ __forceinline__ unsigned short f2bf(float x) {   // RNE bf16
    unsigned int u = __float_as_uint(x);
    u += 0x7fffu + ((u >> 16) & 1u);
    return (unsigned short)(u >> 16);
}
__device__ __forceinline__ float bf2f(unsigned short h) {
    return __uint_as_float((unsigned int)h << 16);
}

// Pack each point into BOTH operand forms (validated slot plan, R7-R9):
//   A-form row: [-2xh,-2yh,-2zh, -2xl,-2yl,-2zl, -2xh,-2yh | -2zh, 1, 1, nh, nl, 0,0,0]
//   B-form col: [  xh,  yh,  zh,   xh,  yh,  zh,   xl,  yl |   zl, nh, nl, 1, 1, 0,0,0]
// => MFMA c = nA + nB - 2*a.b (squared distance; ll term dropped, err ~1e-3)
// Fragment layout (32x32x16): lane holds (row|col)=lane&31, k = 8*(lane>>5)+kk.
__global__ __launch_bounds__(256) void pack_kernel(
        const float* __restrict__ pred, const float* __restrict__ gt,
        uint4* __restrict__ Aform, uint4* __restrict__ Bform) {
    int id    = blockIdx.x * 256 + threadIdx.x;  // [0, 131072)
    int cloud = id >> 16;                        // 0 = pred, 1 = gt
    int rem   = id & 65535;
    int b     = rem >> 14;
    int t2    = rem & 16383;
    int blk   = t2 >> 6;                         // 32-point block [0,256)
    int lane  = t2 & 63;
    int h     = lane >> 5;
    int row   = blk * 32 + (lane & 31);

    const float* s = (cloud ? gt : pred) + ((size_t)b * N + row) * 3;
    float x = s[0], y = s[1], z = s[2];
    unsigned short xh = f2bf(x), yh = f2bf(y), zh = f2bf(z);
    float xl = x - bf2f(xh), yl = y - bf2f(yh), zl = z - bf2f(zh);
    float n = fmaf(x, x, fmaf(y, y, z * z));
    unsigned short nh = f2bf(n);
    unsigned short nl = f2bf(n - bf2f(nh));
    const unsigned short ONE = 0x3F80;

    unsigned short wa[8], wb[8];
    unsigned short mxh = f2bf(-2.f * bf2f(xh));
    unsigned short myh = f2bf(-2.f * bf2f(yh));
    unsigned short mzh = f2bf(-2.f * bf2f(zh));
    if (h == 0) {
        wa[0] = mxh; wa[1] = myh; wa[2] = mzh;
        wa[3] = f2bf(-2.f * xl); wa[4] = f2bf(-2.f * yl); wa[5] = f2bf(-2.f * zl);
        wa[6] = mxh; wa[7] = myh;
        wb[0] = xh; wb[1] = yh; wb[2] = zh;
        wb[3] = xh; wb[4] = yh; wb[5] = zh;
        wb[6] = f2bf(xl); wb[7] = f2bf(yl);
    } else {
        wa[0] = mzh; wa[1] = ONE; wa[2] = ONE; wa[3] = nh; wa[4] = nl;
        wa[5] = 0; wa[6] = 0; wa[7] = 0;
        wb[0] = f2bf(zl); wb[1] = nh; wb[2] = nl; wb[3] = ONE; wb[4] = ONE;
        wb[5] = 0; wb[6] = 0; wb[7] = 0;
    }
    uint4 oa, ob;
    oa.x = (unsigned)wa[0] | ((unsigned)wa[1] << 16);
    oa.y = (unsigned)wa[2] | ((unsigned)wa[3] << 16);
    oa.z = (unsigned)wa[4] | ((unsigned)wa[5] << 16);
    oa.w = (unsigned)wa[6] | ((unsigned)wa[7] << 16);
    ob.x = (unsigned)wb[0] | ((unsigned)wb[1] << 16);
    ob.y = (unsigned)wb[2] | ((unsigned)wb[3] << 16);
    ob.z = (unsigned)wb[4] | ((unsigned)wb[5] << 16);
    ob.w = (unsigned)wb[6] | ((unsigned)wb[7] << 16);
    size_t off = (((size_t)cloud * B + b) * 256 + blk) * 64 + lane;
    Aform[off] = oa;
    Bform[off] = ob;
}

// Both directions use only the cheap col-min path (tree over 16 regs +
// shfl_xor(32)); dir 1 swaps operands. No LDS, no barriers.
// __launch_bounds__(256,4): cap VGPR at 128 so >=4 waves/EU stay resident
// (R7 showed 25% occupancy / latency-bound). unroll 2 keeps prefetch depth
// shallow instead of hoisting all 8 B-fragment loads into registers.
__global__ __launch_bounds__(256, 4) void chamfer_mfma(
        const uint4* __restrict__ Aform, const uint4* __restrict__ Bform,
        unsigned short* __restrict__ part) {
    int wave = blockIdx.x * 4 + (threadIdx.x >> 6);
    int lane = threadIdx.x & 63;
    int js   = wave & (JSTR - 1);
    int r    = wave / JSTR;
    int is   = r & (ISTR - 1);
    r /= ISTR;
    int b    = r & (B - 1);
    int dir  = r / B;                 // 0: minimize over pred; 1: over gt
    int Acl  = dir ? 1 : 0;           // A-side cloud (rows, minimized over)
    int Bcl  = 1 - Acl;               // B-side cloud (cols, output)

    s16x8 afr[IB];
#pragma unroll
    for (int ib = 0; ib < IB; ++ib)
        afr[ib] = __builtin_bit_cast(s16x8,
            Aform[(((size_t)Acl * B + b) * 256 + is * IB + ib) * 64 + lane]);

    const uint4* bbase = Bform + (((size_t)Bcl * B + b) * 256 + js * JT) * 64 + lane;
    unsigned short* po = part + (((size_t)dir * B + b) * ISTR + is) * N + js * JT * 32;

#pragma unroll 2
    for (int jt = 0; jt < JT; ++jt) {
        s16x8 bfr = __builtin_bit_cast(s16x8, bbase[(size_t)jt * 64]);
        float acc = FLT_MAX;
#pragma unroll
        for (int ib = 0; ib < IB; ++ib) {
            f32x16 zc = {};
            f32x16 c = __builtin_amdgcn_mfma_f32_32x32x16_bf16(afr[ib], bfr, zc, 0, 0, 0);
            // col-min tree over this lane's 16 rows (v_min3 fusion)
            float u0 = fminf(fminf(c[0], c[1]), c[2]);
            float u1 = fminf(fminf(c[3], c[4]), c[5]);
            float u2 = fminf(fminf(c[6], c[7]), c[8]);
            float u3 = fminf(fminf(c[9], c[10]), c[11]);
            float u4 = fminf(fminf(c[12], c[13]), c[14]);
            float m  = fminf(fminf(u0, u1),
                             fminf(fminf(u2, u3), fminf(u4, c[15])));
            acc = fminf(acc, m);
        }
        float colmin = fminf(acc, __shfl_xor(acc, 32));   // other 16 rows
        if (lane < 32)
            po[jt * 32 + lane] = f2bf(colmin);
    }
}

// 256 blocks: seg = bk>>5; min over 64 i-strips -> block sum/max partials;
// last-done block combines the 256 partial pairs (counter tail, R4-proven).
__global__ __launch_bounds__(256) void reduce_final(
        const unsigned short* __restrict__ part,
        float* __restrict__ bsum, float* __restrict__ bmax,
        unsigned int* __restrict__ counter, float* __restrict__ out) {
    int bk  = blockIdx.x;
    int seg = bk >> 5;                 // 0..7
    int idx = (bk & 31) * 256 + threadIdx.x;
    const unsigned short* base = part + (size_t)seg * ISTR * N + idx;
    float v = FLT_MAX;
#pragma unroll 8
    for (int s = 0; s < ISTR; ++s)
        v = fminf(v, bf2f(base[(size_t)s * N]));
    __shared__ float ssum[256], smax[256];
    ssum[threadIdx.x] = v;
    smax[threadIdx.x] = v;
    __syncthreads();
    for (int st = 128; st > 0; st >>= 1) {
        if (threadIdx.x < st) {
            ssum[threadIdx.x] += ssum[threadIdx.x + st];
            smax[threadIdx.x] = fmaxf(smax[threadIdx.x], smax[threadIdx.x + st]);
        }
        __syncthreads();
    }
    __shared__ unsigned int s_old;
    if (threadIdx.x == 0) {
        bsum[bk] = ssum[0];
        bmax[bk] = smax[0];
        __threadfence();   // publish partials before counter bump
        s_old = __hip_atomic_fetch_add(counter, 1u, __ATOMIC_ACQ_REL,
                                       __HIP_MEMORY_SCOPE_AGENT);
    }
    __syncthreads();
    if (s_old != 255u) return;

    // Last block: combine 256 partial pairs (agent-scope loads).
    int t = threadIdx.x;
    float ps = __uint_as_float(__hip_atomic_load(
        (const unsigned int*)(bsum + t), __ATOMIC_RELAXED, __HIP_MEMORY_SCOPE_AGENT));
    float pm = __uint_as_float(__hip_atomic_load(
        (const unsigned int*)(bmax + t), __ATOMIC_RELAXED, __HIP_MEMORY_SCOPE_AGENT));
    __syncthreads();   // reuse ssum/smax
    ssum[t] = ps;
    smax[t] = pm;
    __syncthreads();
    for (int st = 128; st > 0; st >>= 1) {
        if (t < st) ssum[t] += ssum[t + st];
        __syncthreads();
    }
    for (int st = 16; st > 0; st >>= 1) {   // per-seg max within each 32-chunk
        if ((t & 31) < st) smax[t] = fmaxf(smax[t], smax[t + st]);
        __syncthreads();
    }
    if (t == 0) {
        float hsum = 0.f;
#pragma unroll
        for (int k = 0; k < NSEG; ++k) hsum += smax[k * 32];
        out[0] = ssum[0] / (float)(B * N);   // chamfer
        out[1] = hsum / (float)B;            // hausdorff
    }
}

extern "C" void kernel_launch(void* const* d_in, const int* in_sizes, int n_in,
                              void* d_out, int out_size, void* d_ws, size_t ws_size,
                              hipStream_t stream) {
    const float* pred = (const float*)d_in[0];
    const float* gt   = (const float*)d_in[1];
    float* out = (float*)d_out;

    char* p = (char*)d_ws;
    uint4* Aform = (uint4*)p;  p += (size_t)2 * B * 256 * 64 * 16;   // 2 MB
    uint4* Bform = (uint4*)p;  p += (size_t)2 * B * 256 * 64 * 16;   // 2 MB
    unsigned short* part = (unsigned short*)p;
    p += (size_t)2 * B * ISTR * N * 2;                               // 8 MB
    float* bsum = (float*)p;   p += 256 * 4;
    float* bmax = (float*)p;   p += 256 * 4;
    unsigned int* counter = (unsigned int*)p;

    hipMemsetAsync(counter, 0, sizeof(unsigned int), stream);
    pack_kernel<<<512, 256, 0, stream>>>(pred, gt, Aform, Bform);
    // waves: dir(2) x b(4) x is(64) x js(32) = 16384 -> 4096 blocks x 4 waves
    chamfer_mfma<<<4096, 256, 0, stream>>>(Aform, Bform, part);
    reduce_final<<<256, 256, 0, stream>>>(part, bsum, bmax, counter, out);
}